// Round 1
// baseline (647.128 us; speedup 1.0000x reference)
//
#include <hip/hip_runtime.h>
#include <hip/hip_bf16.h>
#include <stdint.h>

#define M_DIM 8192
#define N_DIM 4096
#define K_DIM 4096
#define NW (N_DIM * K_DIM)   // 16777216 weight elements

typedef __bf16 bf16x8 __attribute__((ext_vector_type(8)));
typedef float  floatx4 __attribute__((ext_vector_type(4)));
typedef unsigned short u16;
typedef unsigned int   u32;

// ---------------- stats: sum(|w*m|), sum((w*m)^2) ----------------
__global__ void zero_stats(double* S) {
    if (threadIdx.x < 2) S[threadIdx.x] = 0.0;
}

__global__ void reduce_moments(const float* __restrict__ w,
                               const float* __restrict__ msk,
                               double* __restrict__ S) {
    const int nv = NW / 4;
    const int stride = gridDim.x * blockDim.x;
    int idx = blockIdx.x * blockDim.x + threadIdx.x;
    float s1 = 0.f, s2 = 0.f;   // per-thread partials are small (~64 elems) -> fp32 fine
    const float4* w4 = (const float4*)w;
    const float4* m4 = (const float4*)msk;
    for (int i = idx; i < nv; i += stride) {
        float4 a = w4[i];
        float4 b = m4[i];
        float p0 = fabsf(a.x * b.x), p1 = fabsf(a.y * b.y);
        float p2 = fabsf(a.z * b.z), p3 = fabsf(a.w * b.w);
        s1 += p0 + p1 + p2 + p3;
        s2 += p0 * p0 + p1 * p1 + p2 * p2 + p3 * p3;
    }
    double d1 = (double)s1, d2 = (double)s2;
    #pragma unroll
    for (int off = 32; off > 0; off >>= 1) {
        d1 += __shfl_down(d1, off);
        d2 += __shfl_down(d2, off);
    }
    __shared__ double sh[8];
    int lane = threadIdx.x & 63;
    int wv = threadIdx.x >> 6;
    if (lane == 0) { sh[wv] = d1; sh[wv + 4] = d2; }
    __syncthreads();
    if (threadIdx.x == 0) {
        atomicAdd(&S[0], sh[0] + sh[1] + sh[2] + sh[3]);
        atomicAdd(&S[1], sh[4] + sh[5] + sh[6] + sh[7]);
    }
}

__global__ void finalize_stats(const double* __restrict__ S, float* __restrict__ st) {
    if (threadIdx.x == 0) {
        const double n = (double)NW;
        double s1 = S[0], s2 = S[1];
        double mean = s1 / n;
        double var = (s2 - s1 * s1 / n) / (n - 1.0);  // ddof=1
        st[0] = (float)(mean + 1e-8);                 // scale
        st[1] = (float)(0.5 * sqrt(var));             // threshold
    }
}

// ---------------- ternarize: {-1,0,+1} as bf16 bit patterns ----------------
__global__ void ternarize(const float* __restrict__ w, const float* __restrict__ msk,
                          const float* __restrict__ st, u16* __restrict__ tw) {
    const float thr = st[1];
    const int i = (blockIdx.x * blockDim.x + threadIdx.x) * 8;
    float4 a0 = *(const float4*)(w + i);
    float4 a1 = *(const float4*)(w + i + 4);
    float4 b0 = *(const float4*)(msk + i);
    float4 b1 = *(const float4*)(msk + i + 4);
    float p[8] = {a0.x * b0.x, a0.y * b0.y, a0.z * b0.z, a0.w * b0.w,
                  a1.x * b1.x, a1.y * b1.y, a1.z * b1.z, a1.w * b1.w};
    union { u16 u[8]; uint4 v; } r;
    #pragma unroll
    for (int j = 0; j < 8; ++j)
        r.u[j] = p[j] > thr ? (u16)0x3F80 : (p[j] < -thr ? (u16)0xBF80 : (u16)0);
    *(uint4*)(tw + i) = r.v;
}

// ---------------- x: fp32 -> bf16 (RTNE) ----------------
__device__ __forceinline__ u16 f2bf(float f) {
    u32 u = __float_as_uint(f);
    u += 0x7FFFu + ((u >> 16) & 1u);
    return (u16)(u >> 16);
}

__global__ void cvt_x(const float* __restrict__ x, u16* __restrict__ y) {
    const int i = (blockIdx.x * blockDim.x + threadIdx.x) * 8;
    float4 a0 = *(const float4*)(x + i);
    float4 a1 = *(const float4*)(x + i + 4);
    union { u16 u[8]; uint4 v; } r;
    r.u[0] = f2bf(a0.x); r.u[1] = f2bf(a0.y); r.u[2] = f2bf(a0.z); r.u[3] = f2bf(a0.w);
    r.u[4] = f2bf(a1.x); r.u[5] = f2bf(a1.y); r.u[6] = f2bf(a1.z); r.u[7] = f2bf(a1.w);
    *(uint4*)(y + i) = r.v;
}

// ---------------- GEMM: C[m,n] = scale * sum_k A[m,k]*B[n,k] + bias[n] ----------------
__device__ __forceinline__ void gld_lds16(const __bf16* g, __bf16* l) {
    __builtin_amdgcn_global_load_lds(
        (__attribute__((address_space(1))) void*)g,
        (__attribute__((address_space(3))) void*)l, 16, 0, 0);
}

__global__ __launch_bounds__(256) void gemm_tern(
        const __bf16* __restrict__ A, const __bf16* __restrict__ B,
        const float* __restrict__ bias, const float* __restrict__ st,
        float* __restrict__ C) {
    __shared__ __bf16 As[128 * 32];
    __shared__ __bf16 Bs[128 * 32];

    const int t = threadIdx.x;
    const int lane = t & 63;
    const int wv = t >> 6;
    const int wm = (wv >> 1) * 64;   // wave row offset in 128x128 tile
    const int wn = (wv & 1) * 64;    // wave col offset
    const int bm = blockIdx.y * 128;
    const int bn = blockIdx.x * 128;

    // staging map: byte offset o = t*16 (+4096 for second issue); row=o/64, k=(o%64)/2
    const int r  = t >> 2;          // 0..63
    const int kk = (t & 3) * 8;     // 0,8,16,24
    const __bf16* ga0 = A + (size_t)(bm + r) * K_DIM + kk;
    const __bf16* ga1 = A + (size_t)(bm + 64 + r) * K_DIM + kk;
    const __bf16* gb0 = B + (size_t)(bn + r) * K_DIM + kk;
    const __bf16* gb1 = B + (size_t)(bn + 64 + r) * K_DIM + kk;
    __bf16* la0 = As + t * 8;
    __bf16* la1 = As + 2048 + t * 8;
    __bf16* lb0 = Bs + t * 8;
    __bf16* lb1 = Bs + 2048 + t * 8;

    floatx4 acc[4][4] = {};

    const int mrow = lane & 15;       // operand row/col within 16
    const int kc = (lane >> 4) * 8;   // k chunk within 32

    for (int k0 = 0; k0 < K_DIM; k0 += 32) {
        __syncthreads();              // previous iter's LDS reads complete
        gld_lds16(ga0 + k0, la0);
        gld_lds16(ga1 + k0, la1);
        gld_lds16(gb0 + k0, lb0);
        gld_lds16(gb1 + k0, lb1);
        __syncthreads();              // staging drained (vmcnt(0) before s_barrier)

        bf16x8 af[4], bfr[4];
        #pragma unroll
        for (int i = 0; i < 4; ++i) {
            af[i]  = *(const bf16x8*)(As + (wm + i * 16 + mrow) * 32 + kc);
            bfr[i] = *(const bf16x8*)(Bs + (wn + i * 16 + mrow) * 32 + kc);
        }
        #pragma unroll
        for (int im = 0; im < 4; ++im)
            #pragma unroll
            for (int in = 0; in < 4; ++in)
                acc[im][in] = __builtin_amdgcn_mfma_f32_16x16x32_bf16(
                    af[im], bfr[in], acc[im][in], 0, 0, 0);
    }

    // epilogue: D layout col=lane&15, row=(lane>>4)*4+reg  (m89/m91-verified)
    const float scale = st[0];
    const int rbase = bm + wm + ((lane >> 4) << 2);
    const int cbase = bn + wn + (lane & 15);
    #pragma unroll
    for (int in = 0; in < 4; ++in) {
        const int col = cbase + in * 16;
        const float bv = bias[col];
        #pragma unroll
        for (int im = 0; im < 4; ++im) {
            const int row = rbase + im * 16;
            #pragma unroll
            for (int rg = 0; rg < 4; ++rg)
                C[(size_t)(row + rg) * N_DIM + col] = acc[im][in][rg] * scale + bv;
        }
    }
}

// ---------------- launcher ----------------
extern "C" void kernel_launch(void* const* d_in, const int* in_sizes, int n_in,
                              void* d_out, int out_size, void* d_ws, size_t ws_size,
                              hipStream_t stream) {
    const float* x    = (const float*)d_in[0];   // [8192,4096]
    const float* w    = (const float*)d_in[1];   // [4096,4096]
    const float* msk  = (const float*)d_in[2];   // [4096,4096]
    const float* bias = (const float*)d_in[3];   // [4096]
    float* out = (float*)d_out;                  // [8192,4096]

    char* ws = (char*)d_ws;
    double* S   = (double*)ws;                              // 16 B sums
    float*  st  = (float*)(ws + 64);                        // scale, threshold
    u16*    tern = (u16*)(ws + 256);                        // 32 MB ternary weights (bf16)
    u16*    xbf  = (u16*)(ws + 256 + (size_t)NW * 2);       // 64 MB x in bf16

    zero_stats<<<1, 64, 0, stream>>>(S);
    reduce_moments<<<1024, 256, 0, stream>>>(w, msk, S);
    finalize_stats<<<1, 64, 0, stream>>>(S, st);
    ternarize<<<NW / (256 * 8), 256, 0, stream>>>(w, msk, st, tern);
    cvt_x<<<(M_DIM * K_DIM) / (256 * 8), 256, 0, stream>>>(x, xbf);

    dim3 grid(N_DIM / 128, M_DIM / 128);   // 32 x 64 tiles
    gemm_tern<<<grid, 256, 0, stream>>>((const __bf16*)xbf, (const __bf16*)tern,
                                        bias, st, out);
}